// Round 1
// baseline (244.099 us; speedup 1.0000x reference)
//
#include <hip/hip_runtime.h>

#define B_TOT   8192
#define F_DIM   256
#define T_TREES 32
#define N_NODES 63
#define P_DIM   8
#define BROWS   64
#define KB      32
#define XS_STRIDE 36   // 32 + 4 pad, keeps float4 alignment (144 B % 16 == 0)
#define SS_STRIDE 65
#define SHRINK  0.1f

__global__ __launch_bounds__(256) void softgbm_kernel(
    const float* __restrict__ x, const float* __restrict__ W,
    const float* __restrict__ bias, const float* __restrict__ phi,
    float* __restrict__ out)
{
    __shared__ float xs[BROWS * XS_STRIDE];
    __shared__ float ws[64 * XS_STRIDE];
    __shared__ float ss[BROWS * SS_STRIDE];
    __shared__ float phis[64 * P_DIM];
    __shared__ float bs[64];

    const int tid = threadIdx.x;
    const int b0  = blockIdx.x * BROWS;
    const int t   = blockIdx.y;

    // stage phi (64x8) and bias (63) for this tree
    phis[tid]       = phi[t * 512 + tid];
    phis[tid + 256] = phi[t * 512 + 256 + tid];
    if (tid < 64) bs[tid] = (tid < N_NODES) ? bias[t * N_NODES + tid] : 0.0f;

    const int tx = tid & 15;     // col group 0..15
    const int ty = tid >> 4;     // row group 0..15
    const int r0 = ty * 4;
    const int c0 = tx * 4;

    float acc[4][4] = {{0.f,0.f,0.f,0.f},{0.f,0.f,0.f,0.f},
                       {0.f,0.f,0.f,0.f},{0.f,0.f,0.f,0.f}};

    const int lr  = tid >> 3;    // 0..31 (staging row)
    const int lc4 = tid & 7;     // 0..7  (staging float4 within 32-wide K tile)

    for (int k0 = 0; k0 < F_DIM; k0 += KB) {
        __syncthreads();
        {
            const float4 v0 = *(const float4*)&x[(b0 + lr)      * F_DIM + k0 + lc4 * 4];
            const float4 v1 = *(const float4*)&x[(b0 + lr + 32) * F_DIM + k0 + lc4 * 4];
            *(float4*)&xs[lr        * XS_STRIDE + lc4 * 4] = v0;
            *(float4*)&xs[(lr + 32) * XS_STRIDE + lc4 * 4] = v1;

            const float4 w0 = *(const float4*)&W[(t * N_NODES + lr) * F_DIM + k0 + lc4 * 4];
            float4 w1 = make_float4(0.f, 0.f, 0.f, 0.f);
            if (lr + 32 < N_NODES)
                w1 = *(const float4*)&W[(t * N_NODES + lr + 32) * F_DIM + k0 + lc4 * 4];
            *(float4*)&ws[lr        * XS_STRIDE + lc4 * 4] = w0;
            *(float4*)&ws[(lr + 32) * XS_STRIDE + lc4 * 4] = w1;
        }
        __syncthreads();

#pragma unroll
        for (int kk = 0; kk < KB; kk += 4) {
            const float4 a0 = *(const float4*)&xs[(r0 + 0) * XS_STRIDE + kk];
            const float4 a1 = *(const float4*)&xs[(r0 + 1) * XS_STRIDE + kk];
            const float4 a2 = *(const float4*)&xs[(r0 + 2) * XS_STRIDE + kk];
            const float4 a3 = *(const float4*)&xs[(r0 + 3) * XS_STRIDE + kk];
            const float4 g0 = *(const float4*)&ws[(c0 + 0) * XS_STRIDE + kk];
            const float4 g1 = *(const float4*)&ws[(c0 + 1) * XS_STRIDE + kk];
            const float4 g2 = *(const float4*)&ws[(c0 + 2) * XS_STRIDE + kk];
            const float4 g3 = *(const float4*)&ws[(c0 + 3) * XS_STRIDE + kk];
#define DOT4(i, j, A, G) \
            acc[i][j] += A.x * G.x; acc[i][j] += A.y * G.y; \
            acc[i][j] += A.z * G.z; acc[i][j] += A.w * G.w;
            DOT4(0,0,a0,g0) DOT4(0,1,a0,g1) DOT4(0,2,a0,g2) DOT4(0,3,a0,g3)
            DOT4(1,0,a1,g0) DOT4(1,1,a1,g1) DOT4(1,2,a1,g2) DOT4(1,3,a1,g3)
            DOT4(2,0,a2,g0) DOT4(2,1,a2,g1) DOT4(2,2,a2,g2) DOT4(2,3,a2,g3)
            DOT4(3,0,a3,g0) DOT4(3,1,a3,g1) DOT4(3,2,a3,g2) DOT4(3,3,a3,g3)
#undef DOT4
        }
    }

    // epilogue: add bias, sigmoid, store to ss
#pragma unroll
    for (int i = 0; i < 4; ++i) {
#pragma unroll
        for (int j = 0; j < 4; ++j) {
            const float z = acc[i][j] + bs[c0 + j];
            const float s = 1.0f / (1.0f + __expf(-z));
            ss[(r0 + i) * SS_STRIDE + (c0 + j)] = s;
        }
    }
    __syncthreads();

    // ---- leaf phase: 4 threads per row, 16 leaves each ----
    const int row = tid >> 2;    // 0..63
    const int sub = tid & 3;     // subtree of 16 leaves: leaves l = sub*16 + j
    const float* srow = &ss[row * SS_STRIDE];

    // depth 0 (node 0, bit = sub>>1) and depth 1 (node 1+(sub>>1), bit = sub&1)
    const float s0 = srow[0];
    const float f0 = (sub & 2) ? s0 : (1.0f - s0);
    const float s1 = srow[1 + (sub >> 1)];
    const float f1 = (sub & 1) ? s1 : (1.0f - s1);
    const float p2 = f0 * f1;

    // depth 2: node 3+sub, bit = j>>3
    const float s2 = srow[3 + sub];
    float q2[2];
    q2[0] = p2 * (1.0f - s2);
    q2[1] = p2 * s2;

    float q3[4];
#pragma unroll
    for (int h = 0; h < 2; ++h) {            // depth 3: nodes 7 + 2*sub + h
        const float s = srow[7 + 2 * sub + h];
        q3[2 * h]     = q2[h] * (1.0f - s);
        q3[2 * h + 1] = q2[h] * s;
    }
    float q4[8];
#pragma unroll
    for (int h = 0; h < 4; ++h) {            // depth 4: nodes 15 + 4*sub + h
        const float s = srow[15 + 4 * sub + h];
        q4[2 * h]     = q3[h] * (1.0f - s);
        q4[2 * h + 1] = q3[h] * s;
    }
    float q5[16];
#pragma unroll
    for (int h = 0; h < 8; ++h) {            // depth 5: nodes 31 + 8*sub + h
        const float s = srow[31 + 8 * sub + h];
        q5[2 * h]     = q4[h] * (1.0f - s);
        q5[2 * h + 1] = q4[h] * s;
    }

    float pred[8] = {0.f,0.f,0.f,0.f,0.f,0.f,0.f,0.f};
#pragma unroll
    for (int j = 0; j < 16; ++j) {
        const int l = sub * 16 + j;
        const float4 ph0 = *(const float4*)&phis[l * 8];
        const float4 ph1 = *(const float4*)&phis[l * 8 + 4];
        const float q = q5[j];
        pred[0] += q * ph0.x; pred[1] += q * ph0.y;
        pred[2] += q * ph0.z; pred[3] += q * ph0.w;
        pred[4] += q * ph1.x; pred[5] += q * ph1.y;
        pred[6] += q * ph1.z; pred[7] += q * ph1.w;
    }

    // reduce over the 4 sub-threads (lanes differing in low 2 bits)
#pragma unroll
    for (int m = 1; m < 4; m <<= 1) {
#pragma unroll
        for (int p = 0; p < 8; ++p)
            pred[p] += __shfl_xor(pred[p], m, 64);
    }

    // each sub-thread commits 2 of the 8 outputs for its row
    const int p0 = sub * 2;
    atomicAdd(&out[(b0 + row) * P_DIM + p0],     SHRINK * pred[p0]);
    atomicAdd(&out[(b0 + row) * P_DIM + p0 + 1], SHRINK * pred[p0 + 1]);
}

extern "C" void kernel_launch(void* const* d_in, const int* in_sizes, int n_in,
                              void* d_out, int out_size, void* d_ws, size_t ws_size,
                              hipStream_t stream) {
    const float* x    = (const float*)d_in[0];
    const float* W    = (const float*)d_in[1];
    const float* bias = (const float*)d_in[2];
    const float* phi  = (const float*)d_in[3];
    float* out = (float*)d_out;

    hipMemsetAsync(out, 0, sizeof(float) * B_TOT * P_DIM, stream);

    dim3 grid(B_TOT / BROWS, T_TREES);
    softgbm_kernel<<<grid, dim3(256), 0, stream>>>(x, W, bias, phi, out);
}

// Round 2
// 153.054 us; speedup vs baseline: 1.5949x; 1.5949x over previous
//
#include <hip/hip_runtime.h>

#define B_TOT   8192
#define F_DIM   256
#define T_TREES 32
#define N_NODES 63
#define P_DIM   8
#define BM      128
#define BN      64
#define BK      128
#define LDK     136          // BK + 8 ushort pad -> row stride 272 B (16B-aligned, bank-balanced)
#define SS_STRIDE 65
#define SHRINK  0.1f

typedef __bf16 bf16_t;
typedef bf16_t bf16x8 __attribute__((ext_vector_type(8)));
typedef float  f32x4  __attribute__((ext_vector_type(4)));
typedef unsigned short ushort8_t __attribute__((ext_vector_type(8)));
typedef unsigned short ushort4_t __attribute__((ext_vector_type(4)));

// round-to-nearest-even fp32 -> bf16 bits
__device__ __forceinline__ unsigned short f2bf(float f) {
    unsigned int u = __float_as_uint(f);
    u += 0x7fffu + ((u >> 16) & 1u);
    return (unsigned short)(u >> 16);
}

__global__ __launch_bounds__(256) void softgbm_mfma(
    const float* __restrict__ x, const float* __restrict__ W,
    const float* __restrict__ bias, const float* __restrict__ phi,
    float* __restrict__ out)
{
    __shared__ union SmemA {
        unsigned short a[BM * LDK];     // 34816 B (GEMM A tile, bf16 bits)
        float ss[BM * SS_STRIDE];       // 33280 B (sigmoid outputs, reused after GEMM)
    } uA;
    __shared__ unsigned short Bs[BN * LDK];   // 17408 B
    __shared__ float phis[64 * P_DIM];        // 2048 B
    __shared__ float bs[64];

    const int tid = threadIdx.x;
    const int t   = blockIdx.x;             // tree (fastest -> x-tile reuse in L2)
    const int b0  = blockIdx.y * BM;        // batch row base

    // stage phi (64x8) + bias (63) once
    phis[tid]       = phi[t * 512 + tid];
    phis[tid + 256] = phi[t * 512 + 256 + tid];
    if (tid < 64) bs[tid] = (tid < N_NODES) ? bias[t * N_NODES + tid] : 0.0f;

    const int wave = tid >> 6;
    const int lane = tid & 63;
    const int quad = lane >> 4;
    const int lm   = lane & 15;

    f32x4 acc[2][4];
#pragma unroll
    for (int mi = 0; mi < 2; ++mi)
#pragma unroll
        for (int ni = 0; ni < 4; ++ni)
            acc[mi][ni] = f32x4{0.f, 0.f, 0.f, 0.f};

    for (int ko = 0; ko < F_DIM; ko += BK) {
        __syncthreads();   // previous iteration's frag reads done
        // ---- stage A: 128x128 fp32 -> bf16 LDS (coalesced float4, 16/thread) ----
#pragma unroll
        for (int i = 0; i < 16; ++i) {
            const int idx = i * 256 + tid;       // float4 index in tile
            const int r   = idx >> 5;            // 32 float4 per row
            const int kc  = idx & 31;
            const float4 v = *(const float4*)&x[(size_t)(b0 + r) * F_DIM + ko + kc * 4];
            ushort4_t h;
            h.x = f2bf(v.x); h.y = f2bf(v.y); h.z = f2bf(v.z); h.w = f2bf(v.w);
            *(ushort4_t*)&uA.a[r * LDK + kc * 4] = h;
        }
        // ---- stage B: 64x128 (rows 0..62 = W nodes, row 63 = zeros) ----
#pragma unroll
        for (int i = 0; i < 8; ++i) {
            const int idx = i * 256 + tid;
            const int r   = idx >> 5;
            const int kc  = idx & 31;
            float4 v = make_float4(0.f, 0.f, 0.f, 0.f);
            if (r < N_NODES)
                v = *(const float4*)&W[(size_t)(t * N_NODES + r) * F_DIM + ko + kc * 4];
            ushort4_t h;
            h.x = f2bf(v.x); h.y = f2bf(v.y); h.z = f2bf(v.z); h.w = f2bf(v.w);
            *(ushort4_t*)&Bs[r * LDK + kc * 4] = h;
        }
        __syncthreads();

        // ---- MFMA: wave computes rows [wave*32, +32) x cols [0,64) ----
#pragma unroll
        for (int ks = 0; ks < BK / 32; ++ks) {
            const int koff = ks * 32 + quad * 8;
            const bf16x8 a0 = __builtin_bit_cast(bf16x8,
                *(ushort8_t*)&uA.a[(wave * 32 + lm) * LDK + koff]);
            const bf16x8 a1 = __builtin_bit_cast(bf16x8,
                *(ushort8_t*)&uA.a[(wave * 32 + 16 + lm) * LDK + koff]);
            bf16x8 b[4];
#pragma unroll
            for (int ni = 0; ni < 4; ++ni)
                b[ni] = __builtin_bit_cast(bf16x8,
                    *(ushort8_t*)&Bs[(ni * 16 + lm) * LDK + koff]);
#pragma unroll
            for (int ni = 0; ni < 4; ++ni) {
                acc[0][ni] = __builtin_amdgcn_mfma_f32_16x16x32_bf16(a0, b[ni], acc[0][ni], 0, 0, 0);
                acc[1][ni] = __builtin_amdgcn_mfma_f32_16x16x32_bf16(a1, b[ni], acc[1][ni], 0, 0, 0);
            }
        }
    }
    __syncthreads();   // all frag reads of uA.a done before ss overwrites it

    // ---- epilogue: bias + sigmoid -> ss[row][col]  (C/D: col=lane&15, row=quad*4+reg) ----
#pragma unroll
    for (int mi = 0; mi < 2; ++mi)
#pragma unroll
        for (int ni = 0; ni < 4; ++ni) {
            const int col = ni * 16 + lm;
            const float bb = bs[col];
#pragma unroll
            for (int reg = 0; reg < 4; ++reg) {
                const int row = wave * 32 + mi * 16 + quad * 4 + reg;
                const float z = acc[mi][ni][reg] + bb;
                uA.ss[row * SS_STRIDE + col] = 1.0f / (1.0f + __expf(-z));
            }
        }
    __syncthreads();

    // ---- tree walk: 2 threads per row, 32 leaves each ----
    const int row = tid >> 1;
    const int h   = tid & 1;
    const float* srow = &uA.ss[row * SS_STRIDE];

    const float s0 = srow[0];
    const float p1 = h ? s0 : (1.0f - s0);
    float q2[2], q3[4], q4[8], q5[16], q6[32];
    {
        const float s = srow[1 + h];
        q2[0] = p1 * (1.0f - s);  q2[1] = p1 * s;
    }
#pragma unroll
    for (int v = 0; v < 2; ++v) {
        const float s = srow[3 + 2 * h + v];
        q3[2 * v] = q2[v] * (1.0f - s);  q3[2 * v + 1] = q2[v] * s;
    }
#pragma unroll
    for (int v = 0; v < 4; ++v) {
        const float s = srow[7 + 4 * h + v];
        q4[2 * v] = q3[v] * (1.0f - s);  q4[2 * v + 1] = q3[v] * s;
    }
#pragma unroll
    for (int v = 0; v < 8; ++v) {
        const float s = srow[15 + 8 * h + v];
        q5[2 * v] = q4[v] * (1.0f - s);  q5[2 * v + 1] = q4[v] * s;
    }
#pragma unroll
    for (int v = 0; v < 16; ++v) {
        const float s = srow[31 + 16 * h + v];
        q6[2 * v] = q5[v] * (1.0f - s);  q6[2 * v + 1] = q5[v] * s;
    }

    float pred[8] = {0.f, 0.f, 0.f, 0.f, 0.f, 0.f, 0.f, 0.f};
#pragma unroll
    for (int j = 0; j < 32; ++j) {
        const int l = 32 * h + j;
        const float4 ph0 = *(const float4*)&phis[l * 8];
        const float4 ph1 = *(const float4*)&phis[l * 8 + 4];
        const float q = q6[j];
        pred[0] += q * ph0.x; pred[1] += q * ph0.y;
        pred[2] += q * ph0.z; pred[3] += q * ph0.w;
        pred[4] += q * ph1.x; pred[5] += q * ph1.y;
        pred[6] += q * ph1.z; pred[7] += q * ph1.w;
    }

    // partner lanes (h=0/1) exchange the half each commits; 4 atomics/thread
#pragma unroll
    for (int i = 0; i < 4; ++i) {
        const float mine   = h ? pred[4 + i] : pred[i];
        const float theirs = h ? pred[i]     : pred[4 + i];
        const float recv   = __shfl_xor(theirs, 1, 64);
        atomicAdd(&out[(size_t)(b0 + row) * P_DIM + h * 4 + i], SHRINK * (mine + recv));
    }
}

extern "C" void kernel_launch(void* const* d_in, const int* in_sizes, int n_in,
                              void* d_out, int out_size, void* d_ws, size_t ws_size,
                              hipStream_t stream) {
    const float* x    = (const float*)d_in[0];
    const float* W    = (const float*)d_in[1];
    const float* bias = (const float*)d_in[2];
    const float* phi  = (const float*)d_in[3];
    float* out = (float*)d_out;

    hipMemsetAsync(out, 0, sizeof(float) * B_TOT * P_DIM, stream);

    dim3 grid(T_TREES, B_TOT / BM);
    softgbm_mfma<<<grid, dim3(256), 0, stream>>>(x, W, bias, phi, out);
}

// Round 3
// 96.423 us; speedup vs baseline: 2.5315x; 1.5873x over previous
//
#include <hip/hip_runtime.h>

#define B_TOT   8192
#define F_DIM   256
#define T_TREES 32
#define N_NODES 63
#define P_DIM   8
#define BM      128
#define SHRINK  0.1f

typedef __bf16 bf16_t;
typedef bf16_t bf16x8 __attribute__((ext_vector_type(8)));
typedef float  f32x4  __attribute__((ext_vector_type(4)));
typedef unsigned short ushort8_t __attribute__((ext_vector_type(8)));
typedef unsigned short ushort4_t __attribute__((ext_vector_type(4)));

__device__ __forceinline__ unsigned short f2bf(float f) {
    unsigned int u = __float_as_uint(f);
    u += 0x7fffu + ((u >> 16) & 1u);
    return (unsigned short)(u >> 16);
}
__device__ __forceinline__ float bf2f(unsigned short h) {
    return __uint_as_float(((unsigned int)h) << 16);
}
__device__ __forceinline__ void gl_lds16(const void* g, void* l) {
    __builtin_amdgcn_global_load_lds(
        (const __attribute__((address_space(1))) unsigned int*)g,
        (__attribute__((address_space(3))) unsigned int*)l, 16, 0, 0);
}

// ---------- convert kernels ----------
__global__ __launch_bounds__(256) void cvt_x(const float* __restrict__ x,
                                             unsigned short* __restrict__ xb) {
    const int i = blockIdx.x * 256 + threadIdx.x;       // float4 index, 524288 total
    const float4 v = *(const float4*)&x[(size_t)i * 4];
    ushort4_t h;
    h.x = f2bf(v.x); h.y = f2bf(v.y); h.z = f2bf(v.z); h.w = f2bf(v.w);
    *(ushort4_t*)&xb[(size_t)i * 4] = h;
}

__global__ __launch_bounds__(256) void cvt_w(const float* __restrict__ W,
                                             unsigned short* __restrict__ Wb) {
    const int i = blockIdx.x * 256 + threadIdx.x;       // float4 index, 131072 total
    const int tree = i >> 12;                           // 4096 float4 per (padded) tree
    const int rem  = i & 4095;
    const int row  = rem >> 6;                          // 0..63
    const int c4   = rem & 63;
    float4 v = make_float4(0.f, 0.f, 0.f, 0.f);
    if (row < N_NODES)
        v = *(const float4*)&W[((size_t)(tree * N_NODES + row)) * F_DIM + c4 * 4];
    ushort4_t h;
    h.x = f2bf(v.x); h.y = f2bf(v.y); h.z = f2bf(v.z); h.w = f2bf(v.w);
    *(ushort4_t*)&Wb[(size_t)i * 4] = h;
}

// phi B-fragments: for MFMA 16x16x32, lane l holds B[k=(l>>4)*8+j][n=l&15].
// phiB[tree][k2][lane][8] bf16, k = k2*32 + quad*8 + j, n<8 from phi else 0.
__global__ __launch_bounds__(256) void cvt_phi(const float* __restrict__ phi,
                                               unsigned short* __restrict__ phiB) {
    const int i = blockIdx.x * 256 + threadIdx.x;       // 0..4095
    const int tree = i >> 7;
    const int rem  = i & 127;
    const int k2   = rem >> 6;
    const int lane = rem & 63;
    const int lm   = lane & 15;
    const int quad = lane >> 4;
    ushort8_t h;
#pragma unroll
    for (int j = 0; j < 8; ++j) {
        float v = 0.f;
        if (lm < 8) v = phi[(size_t)tree * 512 + (k2 * 32 + quad * 8 + j) * 8 + lm];
        h[j] = f2bf(v);
    }
    *(ushort8_t*)&phiB[(size_t)i * 8] = h;
}

// ---------- main fused kernel ----------
__global__ __launch_bounds__(256, 2) void softgbm_main(
    const unsigned short* __restrict__ xb, const unsigned short* __restrict__ Wb,
    const unsigned short* __restrict__ phiB, const float* __restrict__ bias,
    float* __restrict__ out)
{
    __shared__ union Smem {
        struct { unsigned short A[BM * 128]; unsigned short B[128 * 128]; } g; // 64 KB
        struct { unsigned short ss[2 * BM * 64]; unsigned short lv[2][BM * 64]; } e; // 64 KB
    } sm;
    __shared__ float bs2[2][64];

    const int tid  = threadIdx.x;
    const int tp   = blockIdx.x;            // tree pair 0..15 (fast dim -> x-tile L2 reuse)
    const int b0   = blockIdx.y * BM;
    const int wave = tid >> 6;
    const int lane = tid & 63;
    const int quad = lane >> 4;
    const int lm   = lane & 15;
    const int wr   = wave >> 1;             // row half 0..1 (64 rows)
    const int wc   = wave & 1;              // tree 0..1 (64 cols)

    if (tid < 128) {
        const int p = tid >> 6, node = tid & 63;
        bs2[p][node] = (node < N_NODES) ? bias[(tp * 2 + p) * N_NODES + node] : 0.f;
    }

    // phi B-frags from global (precomputed lane-ordered layout), 4x b128
    bf16x8 pb[2][2];
#pragma unroll
    for (int p = 0; p < 2; ++p)
#pragma unroll
        for (int k2 = 0; k2 < 2; ++k2)
            pb[p][k2] = __builtin_bit_cast(bf16x8,
                *(const ushort8_t*)&phiB[(size_t)(((tp * 2 + p) * 2 + k2) * 64 + lane) * 8]);

    f32x4 acc[4][4];
#pragma unroll
    for (int m = 0; m < 4; ++m)
#pragma unroll
        for (int n = 0; n < 4; ++n)
            acc[m][n] = f32x4{0.f, 0.f, 0.f, 0.f};

    // ---- GEMM: C[128 x 128cols(2 trees x 64 nodes)] = xb . Wb^T, K=256 ----
    for (int ko = 0; ko < F_DIM; ko += 128) {
        __syncthreads();
        // async stage A (128x128 bf16): 8 x 1KB wave-loads; swizzle chunk^=(row&7)
#pragma unroll
        for (int i = 0; i < 8; ++i) {
            const int r4 = wave * 8 + i;
            const int r  = r4 * 4 + (lane >> 4);
            const int c  = (lane & 15) ^ (r & 7);
            gl_lds16(&xb[(size_t)(b0 + r) * F_DIM + ko + c * 8],
                     (char*)sm.g.A + r4 * 1024);
        }
        // async stage B (128 node-rows = 2 trees x 64)
#pragma unroll
        for (int i = 0; i < 8; ++i) {
            const int r4 = wave * 8 + i;
            const int nr = r4 * 4 + (lane >> 4);
            const int c  = (lane & 15) ^ (nr & 7);
            gl_lds16(&Wb[(size_t)(tp * 128 + nr) * F_DIM + ko + c * 8],
                     (char*)sm.g.B + r4 * 1024);
        }
        __syncthreads();

#pragma unroll
        for (int ks = 0; ks < 4; ++ks) {
            bf16x8 af[4], bf[4];
#pragma unroll
            for (int m = 0; m < 4; ++m) {
                const int r  = wr * 64 + m * 16 + lm;
                const int cp = (ks * 4 + quad) ^ (r & 7);
                af[m] = __builtin_bit_cast(bf16x8, *(ushort8_t*)&sm.g.A[r * 128 + cp * 8]);
            }
#pragma unroll
            for (int n = 0; n < 4; ++n) {
                const int r  = wc * 64 + n * 16 + lm;
                const int cp = (ks * 4 + quad) ^ (r & 7);
                bf[n] = __builtin_bit_cast(bf16x8, *(ushort8_t*)&sm.g.B[r * 128 + cp * 8]);
            }
#pragma unroll
            for (int m = 0; m < 4; ++m)
#pragma unroll
                for (int n = 0; n < 4; ++n)
                    acc[m][n] = __builtin_amdgcn_mfma_f32_16x16x32_bf16(af[m], bf[n], acc[m][n], 0, 0, 0);
        }
    }
    __syncthreads();   // frag reads done; LDS becomes epilogue space

    // ---- sigmoid -> ss[wc] (bf16, chunk-swizzled). C/D: col=lane&15, row=quad*4+reg ----
#pragma unroll
    for (int m = 0; m < 4; ++m)
#pragma unroll
        for (int n = 0; n < 4; ++n) {
            const int node = n * 16 + lm;
            const float bb = bs2[wc][node];
#pragma unroll
            for (int reg = 0; reg < 4; ++reg) {
                const int row = wr * 64 + m * 16 + quad * 4 + reg;
                const float z = acc[m][n][reg] + bb;
                const float s = 1.0f / (1.0f + __expf(-z));
                const int cp = (node >> 3) ^ (row & 7);
                sm.e.ss[wc * (BM * 64) + row * 64 + cp * 8 + (node & 7)] = f2bf(s);
            }
        }
    __syncthreads();

    f32x4 accp[2] = { f32x4{0.f,0.f,0.f,0.f}, f32x4{0.f,0.f,0.f,0.f} };

    for (int p = 0; p < 2; ++p) {
        // ---- tree walk: thread=(row,h), reads ss[p], writes lv[p] as bf16 ----
        {
            const int row = tid >> 1;
            const int h   = tid & 1;
            const unsigned short* sr = &sm.e.ss[p * (BM * 64) + row * 64];
            const int rs = row & 7;
#define RDS(j) bf2f(sr[(((j) >> 3) ^ rs) * 8 + ((j) & 7)])
            const float s0 = RDS(0);
            const float p1 = h ? s0 : (1.0f - s0);
            float q2[2], q3[4], q4[8], q5[16], q6[32];
            {
                const float s = RDS(1 + h);
                q2[0] = p1 * (1.0f - s); q2[1] = p1 * s;
            }
#pragma unroll
            for (int v = 0; v < 2; ++v) {
                const float s = RDS(3 + 2 * h + v);
                q3[2 * v] = q2[v] * (1.0f - s); q3[2 * v + 1] = q2[v] * s;
            }
#pragma unroll
            for (int v = 0; v < 4; ++v) {
                const float s = RDS(7 + 4 * h + v);
                q4[2 * v] = q3[v] * (1.0f - s); q4[2 * v + 1] = q3[v] * s;
            }
#pragma unroll
            for (int v = 0; v < 8; ++v) {
                const float s = RDS(15 + 8 * h + v);
                q5[2 * v] = q4[v] * (1.0f - s); q5[2 * v + 1] = q4[v] * s;
            }
#pragma unroll
            for (int v = 0; v < 16; ++v) {
                const float s = RDS(31 + 16 * h + v);
                q6[2 * v] = q5[v] * (1.0f - s); q6[2 * v + 1] = q5[v] * s;
            }
#undef RDS
            unsigned short* lr = &sm.e.lv[p][row * 64];
#pragma unroll
            for (int j = 0; j < 32; j += 2) {
                const int l  = h * 32 + j;
                const int cp = ((l >> 3) ^ rs);
                const unsigned int pack =
                    (unsigned int)f2bf(q6[j]) | ((unsigned int)f2bf(q6[j + 1]) << 16);
                *(unsigned int*)&lr[cp * 8 + (l & 7)] = pack;
            }
        }
        __syncthreads();

        // ---- phi contraction via MFMA: rows wave*32 + mg*16, K=64 leaves ----
#pragma unroll
        for (int mg = 0; mg < 2; ++mg) {
#pragma unroll
            for (int k2 = 0; k2 < 2; ++k2) {
                const int row = wave * 32 + mg * 16 + lm;
                const int cp  = (k2 * 4 + quad) ^ (row & 7);
                const bf16x8 afr = __builtin_bit_cast(bf16x8,
                    *(ushort8_t*)&sm.e.lv[p][row * 64 + cp * 8]);
                accp[mg] = __builtin_amdgcn_mfma_f32_16x16x32_bf16(afr, pb[p][k2], accp[mg], 0, 0, 0);
            }
        }
        // next iteration's walk writes lv[1] (disjoint from lv[0] reads); its
        // __syncthreads() orders everything before phi1 reads lv[1].
    }

    // ---- commit: col=lm (0..7 valid), row=quad*4+reg ----
    if (lm < P_DIM) {
#pragma unroll
        for (int mg = 0; mg < 2; ++mg)
#pragma unroll
            for (int reg = 0; reg < 4; ++reg) {
                const int row = wave * 32 + mg * 16 + quad * 4 + reg;
                atomicAdd(&out[(size_t)(b0 + row) * P_DIM + lm], SHRINK * accp[mg][reg]);
            }
    }
}

extern "C" void kernel_launch(void* const* d_in, const int* in_sizes, int n_in,
                              void* d_out, int out_size, void* d_ws, size_t ws_size,
                              hipStream_t stream) {
    const float* x    = (const float*)d_in[0];
    const float* W    = (const float*)d_in[1];
    const float* bias = (const float*)d_in[2];
    const float* phi  = (const float*)d_in[3];
    float* out = (float*)d_out;

    unsigned short* xb   = (unsigned short*)d_ws;                    // 8192*256
    unsigned short* Wb   = xb + (size_t)B_TOT * F_DIM;               // 32*64*256
    unsigned short* phiB = Wb + (size_t)T_TREES * 64 * F_DIM;        // 32*2*64*8

    cvt_x  <<<dim3((B_TOT * F_DIM / 4) / 256), dim3(256), 0, stream>>>(x, xb);
    cvt_w  <<<dim3((T_TREES * 64 * F_DIM / 4) / 256), dim3(256), 0, stream>>>(W, Wb);
    cvt_phi<<<dim3(16), dim3(256), 0, stream>>>(phi, phiB);
    hipMemsetAsync(out, 0, sizeof(float) * B_TOT * P_DIM, stream);

    dim3 grid(T_TREES / 2, B_TOT / BM);
    softgbm_main<<<grid, dim3(256), 0, stream>>>(xb, Wb, phiB, bias, out);
}

// Round 4
// 91.448 us; speedup vs baseline: 2.6693x; 1.0544x over previous
//
#include <hip/hip_runtime.h>

#define B_TOT   8192
#define F_DIM   256
#define T_TREES 32
#define N_NODES 63
#define P_DIM   8
#define BM      128
#define SHRINK  0.1f

typedef __bf16 bf16_t;
typedef bf16_t bf16x8 __attribute__((ext_vector_type(8)));
typedef float  f32x4  __attribute__((ext_vector_type(4)));
typedef unsigned short ushort8_t __attribute__((ext_vector_type(8)));
typedef unsigned short ushort4_t __attribute__((ext_vector_type(4)));

__device__ __forceinline__ unsigned short f2bf(float f) {
    unsigned int u = __float_as_uint(f);
    u += 0x7fffu + ((u >> 16) & 1u);
    return (unsigned short)(u >> 16);
}
// pack two floats -> 2x bf16 (RNE) in one u32
__device__ __forceinline__ unsigned int pk2bf(float a, float b) {
    unsigned int ua = __float_as_uint(a); ua += 0x7fffu + ((ua >> 16) & 1u);
    unsigned int ub = __float_as_uint(b); ub += 0x7fffu + ((ub >> 16) & 1u);
    return (ua >> 16) | (ub & 0xffff0000u);
}
__device__ __forceinline__ void gl_lds16(const void* g, void* l) {
    __builtin_amdgcn_global_load_lds(
        (const __attribute__((address_space(1))) unsigned int*)g,
        (__attribute__((address_space(3))) unsigned int*)l, 16, 0, 0);
}

// ---------- fused convert kernel (x, W-padded, phi B-frags) ----------
__global__ __launch_bounds__(256) void cvt_all(
    const float* __restrict__ x, const float* __restrict__ W,
    const float* __restrict__ phi,
    unsigned short* __restrict__ xb, unsigned short* __restrict__ Wb,
    unsigned short* __restrict__ phiB)
{
    const int bx  = blockIdx.x;
    const int tid = threadIdx.x;
    if (bx < 2048) {                       // x: 524288 float4
        const int i = bx * 256 + tid;
        const float4 v = *(const float4*)&x[(size_t)i * 4];
        ushort4_t h;
        h.x = f2bf(v.x); h.y = f2bf(v.y); h.z = f2bf(v.z); h.w = f2bf(v.w);
        *(ushort4_t*)&xb[(size_t)i * 4] = h;
    } else if (bx < 2560) {                // W: pad 63->64 rows/tree, 131072 float4
        const int i = (bx - 2048) * 256 + tid;
        const int tree = i >> 12;
        const int rem  = i & 4095;
        const int row  = rem >> 6;
        const int c4   = rem & 63;
        float4 v = make_float4(0.f, 0.f, 0.f, 0.f);
        if (row < N_NODES)
            v = *(const float4*)&W[((size_t)(tree * N_NODES + row)) * F_DIM + c4 * 4];
        ushort4_t h;
        h.x = f2bf(v.x); h.y = f2bf(v.y); h.z = f2bf(v.z); h.w = f2bf(v.w);
        *(ushort4_t*)&Wb[(size_t)i * 4] = h;
    } else {                               // phi B-frags: lane l holds B[k=quad*8+j][n=l&15]
        const int i = (bx - 2560) * 256 + tid;   // 0..4095
        const int tree = i >> 7;
        const int rem  = i & 127;
        const int k2   = rem >> 6;
        const int lane = rem & 63;
        const int lm   = lane & 15;
        const int quad = lane >> 4;
        ushort8_t h;
#pragma unroll
        for (int j = 0; j < 8; ++j) {
            float v = 0.f;
            if (lm < 8) v = phi[(size_t)tree * 512 + (k2 * 32 + quad * 8 + j) * 8 + lm];
            h[j] = f2bf(v);
        }
        *(ushort8_t*)&phiB[(size_t)i * 8] = h;
    }
}

// ---------- main fused kernel ----------
__global__ __launch_bounds__(256, 3) void softgbm_main(
    const unsigned short* __restrict__ xb, const unsigned short* __restrict__ Wb,
    const unsigned short* __restrict__ phiB, const float* __restrict__ bias,
    float* __restrict__ out)
{
    __shared__ union Smem {
        struct { unsigned short A[BM * 64]; unsigned short B[BM * 64]; } g; // 32 KB
        unsigned short ss[2][BM * 64];                                      // 32 KB
    } sm;
    __shared__ unsigned short lv[BM * 64];                                  // 16 KB
    __shared__ float bs2[2][64];

    const int tid  = threadIdx.x;
    const int tp   = blockIdx.x;            // tree pair 0..15
    const int b0   = blockIdx.y * BM;
    const int wave = tid >> 6;
    const int lane = tid & 63;
    const int quad = lane >> 4;
    const int lm   = lane & 15;
    const int wr   = wave >> 1;             // row half (64 rows)
    const int wc   = wave & 1;              // tree within pair

    if (tid < 128) {
        const int p = tid >> 6, node = tid & 63;
        bs2[p][node] = (node < N_NODES) ? bias[(tp * 2 + p) * N_NODES + node] : 0.f;
    }

    f32x4 acc[4][4];
#pragma unroll
    for (int m = 0; m < 4; ++m)
#pragma unroll
        for (int n = 0; n < 4; ++n)
            acc[m][n] = f32x4{0.f, 0.f, 0.f, 0.f};

    // ---- GEMM: C[128 x (2 trees x 64 nodes)] = xb . Wb^T, K=256, BK=64 ----
    for (int ko = 0; ko < F_DIM; ko += 64) {
        __syncthreads();
#pragma unroll
        for (int i = 0; i < 4; ++i) {       // A: 1 KB per wave-iter, 8 rows x 128 B
            const int r = wave * 32 + i * 8 + (lane >> 3);
            const int c = (lane & 7) ^ (r & 7);
            gl_lds16(&xb[(size_t)(b0 + r) * F_DIM + ko + c * 8],
                     &sm.g.A[(wave * 32 + i * 8) * 64]);
        }
#pragma unroll
        for (int i = 0; i < 4; ++i) {       // B: 128 node-rows (2 trees)
            const int r = wave * 32 + i * 8 + (lane >> 3);
            const int c = (lane & 7) ^ (r & 7);
            gl_lds16(&Wb[(size_t)(tp * 128 + r) * F_DIM + ko + c * 8],
                     &sm.g.B[(wave * 32 + i * 8) * 64]);
        }
        __syncthreads();

#pragma unroll
        for (int ks = 0; ks < 2; ++ks) {
            bf16x8 af[4], bfr[4];
#pragma unroll
            for (int m = 0; m < 4; ++m) {
                const int r  = wr * 64 + m * 16 + lm;
                const int cp = (ks * 4 + quad) ^ (r & 7);
                af[m] = __builtin_bit_cast(bf16x8, *(ushort8_t*)&sm.g.A[r * 64 + cp * 8]);
            }
#pragma unroll
            for (int n = 0; n < 4; ++n) {
                const int r  = wc * 64 + n * 16 + lm;
                const int cp = (ks * 4 + quad) ^ (r & 7);
                bfr[n] = __builtin_bit_cast(bf16x8, *(ushort8_t*)&sm.g.B[r * 64 + cp * 8]);
            }
#pragma unroll
            for (int m = 0; m < 4; ++m)
#pragma unroll
                for (int n = 0; n < 4; ++n)
                    acc[m][n] = __builtin_amdgcn_mfma_f32_16x16x32_bf16(af[m], bfr[n], acc[m][n], 0, 0, 0);
        }
    }
    __syncthreads();   // all frag reads done; LDS becomes ss space

    // phi B-frags (issued early, consumed in phi-MFMA phase)
    bf16x8 pb[2][2];
#pragma unroll
    for (int p = 0; p < 2; ++p)
#pragma unroll
        for (int k2 = 0; k2 < 2; ++k2)
            pb[p][k2] = __builtin_bit_cast(bf16x8,
                *(const ushort8_t*)&phiB[(size_t)(((tp * 2 + p) * 2 + k2) * 64 + lane) * 8]);

    // ---- sigmoid: wave's tree = wc; ss[wc][row][node] chunk-swizzled ----
#pragma unroll
    for (int m = 0; m < 4; ++m)
#pragma unroll
        for (int n = 0; n < 4; ++n) {
            const int node = n * 16 + lm;
            const float bb = bs2[wc][node];
#pragma unroll
            for (int reg = 0; reg < 4; ++reg) {
                const int row = wr * 64 + m * 16 + quad * 4 + reg;
                const float z = acc[m][n][reg] + bb;
                const float s = __frcp_rn(1.0f + __expf(-z));
                const int slot = (node >> 3) ^ (row & 7);
                sm.ss[wc][row * 64 + slot * 8 + (node & 7)] = f2bf(s);
            }
        }
    __syncthreads();

    f32x4 accp[2] = { f32x4{0.f,0.f,0.f,0.f}, f32x4{0.f,0.f,0.f,0.f} };

    const int row = tid >> 1;
    const int h   = tid & 1;
    const int rs  = row & 7;

    for (int p = 0; p < 2; ++p) {
        // ---- walk: whole row into registers via 8x b128 ----
        const unsigned short* sp = &sm.ss[p][row * 64];
        unsigned int cw[32];
#pragma unroll
        for (int c = 0; c < 8; ++c)
            *(uint4*)&cw[c * 4] = *(const uint4*)&sp[(c ^ rs) * 8];

#define NV(j) ((j) & 1 ? __uint_as_float(cw[(j) >> 1] & 0xffff0000u) \
                       : __uint_as_float(cw[(j) >> 1] << 16))
#define SEL(a, b) (h ? NV(b) : NV(a))
        const float s0v = NV(0);
        const float q1  = h ? s0v : (1.0f - s0v);
        float q2[2], q3[4], q4[8], q5[16], q6[32];
        {
            const float t = SEL(1, 2);
            q2[1] = q1 * t; q2[0] = q1 - q2[1];
        }
#pragma unroll
        for (int v = 0; v < 2; ++v) {
            const float t = SEL(3 + v, 5 + v);
            q3[2 * v + 1] = q2[v] * t; q3[2 * v] = q2[v] - q3[2 * v + 1];
        }
#pragma unroll
        for (int v = 0; v < 4; ++v) {
            const float t = SEL(7 + v, 11 + v);
            q4[2 * v + 1] = q3[v] * t; q4[2 * v] = q3[v] - q4[2 * v + 1];
        }
#pragma unroll
        for (int v = 0; v < 8; ++v) {
            const float t = SEL(15 + v, 23 + v);
            q5[2 * v + 1] = q4[v] * t; q5[2 * v] = q4[v] - q5[2 * v + 1];
        }
#pragma unroll
        for (int v = 0; v < 16; ++v) {
            const float t = SEL(31 + v, 47 + v);
            q6[2 * v + 1] = q5[v] * t; q6[2 * v] = q5[v] - q6[2 * v + 1];
        }
#undef SEL
#undef NV
        // leaves -> lv (bf16, A-frag swizzled layout), 4x b128 per thread
#pragma unroll
        for (int i = 0; i < 4; ++i) {
            uint4 w;
            w.x = pk2bf(q6[i * 8 + 0], q6[i * 8 + 1]);
            w.y = pk2bf(q6[i * 8 + 2], q6[i * 8 + 3]);
            w.z = pk2bf(q6[i * 8 + 4], q6[i * 8 + 5]);
            w.w = pk2bf(q6[i * 8 + 6], q6[i * 8 + 7]);
            *(uint4*)&lv[row * 64 + (((h * 4 + i) ^ rs)) * 8] = w;
        }
        __syncthreads();

        // ---- phi contraction via MFMA: rows wave*32 + mg*16, K=64 leaves ----
#pragma unroll
        for (int mg = 0; mg < 2; ++mg) {
#pragma unroll
            for (int k2 = 0; k2 < 2; ++k2) {
                const int r2 = wave * 32 + mg * 16 + lm;
                const int cp = (k2 * 4 + quad) ^ (r2 & 7);
                const bf16x8 afr = __builtin_bit_cast(bf16x8,
                    *(ushort8_t*)&lv[r2 * 64 + cp * 8]);
                accp[mg] = __builtin_amdgcn_mfma_f32_16x16x32_bf16(afr, pb[p][k2], accp[mg], 0, 0, 0);
            }
        }
        __syncthreads();   // phi reads done before next p's walk overwrites lv
    }

    // ---- commit: col=lm (0..7), row=quad*4+reg ----
    if (lm < P_DIM) {
#pragma unroll
        for (int mg = 0; mg < 2; ++mg)
#pragma unroll
            for (int reg = 0; reg < 4; ++reg) {
                const int r2 = wave * 32 + mg * 16 + quad * 4 + reg;
                atomicAdd(&out[(size_t)(b0 + r2) * P_DIM + lm], SHRINK * accp[mg][reg]);
            }
    }
}

extern "C" void kernel_launch(void* const* d_in, const int* in_sizes, int n_in,
                              void* d_out, int out_size, void* d_ws, size_t ws_size,
                              hipStream_t stream) {
    const float* x    = (const float*)d_in[0];
    const float* W    = (const float*)d_in[1];
    const float* bias = (const float*)d_in[2];
    const float* phi  = (const float*)d_in[3];
    float* out = (float*)d_out;

    unsigned short* xb   = (unsigned short*)d_ws;                    // 8192*256
    unsigned short* Wb   = xb + (size_t)B_TOT * F_DIM;               // 32*64*256
    unsigned short* phiB = Wb + (size_t)T_TREES * 64 * F_DIM;        // 32*2*64*8

    hipMemsetAsync(out, 0, sizeof(float) * B_TOT * P_DIM, stream);
    cvt_all<<<dim3(2576), dim3(256), 0, stream>>>(x, W, phi, xb, Wb, phiB);

    dim3 grid(T_TREES / 2, B_TOT / BM);
    softgbm_main<<<grid, dim3(256), 0, stream>>>(xb, Wb, phiB, bias, out);
}